// Round 1
// baseline (580.900 us; speedup 1.0000x reference)
//
#include <hip/hip_runtime.h>
#include <stdint.h>

#define NEXP 8
#define HD 1024
#define ID 3584
#define NTOK 2048
#define NSLOT 4096          // NTOK * TOPK
#define SLOT_PAD 128
#define NSLOT_ALLOC (NSLOT + SLOT_PAD)

#define BM 128
#define BN 128
#define BK 32

typedef __attribute__((ext_vector_type(8))) short s16x8;
typedef __attribute__((ext_vector_type(4))) short s16x4;
typedef __attribute__((ext_vector_type(4))) float f32x4;
typedef __attribute__((ext_vector_type(4))) int   i32x4;

__device__ __forceinline__ unsigned short f2bf(float f) {
    union { float f; unsigned int u; } v; v.f = f;
    unsigned int r = v.u + 0x7FFFu + ((v.u >> 16) & 1u);  // RNE
    return (unsigned short)(r >> 16);
}

// ---------------- K0: zero counters ----------------
__global__ void init_kernel(int* __restrict__ counts) {
    if (threadIdx.x < 16) counts[threadIdx.x] = 0;   // counts[8] + counts2[8]
}

// ---------------- K1: router (fp32, exact top-2) ----------------
__global__ void router_kernel(const float* __restrict__ x, const float* __restrict__ wg,
                              int* __restrict__ topk_idx, float* __restrict__ topk_w,
                              int* __restrict__ counts) {
    int t = blockIdx.x;
    int lane = threadIdx.x;   // 64 threads = 1 wave
    float acc[NEXP];
#pragma unroll
    for (int e = 0; e < NEXP; ++e) acc[e] = 0.f;
    const float* xr = x + (size_t)t * HD;
    for (int h = lane; h < HD; h += 64) {
        float xv = xr[h];
#pragma unroll
        for (int e = 0; e < NEXP; ++e) acc[e] += xv * wg[e * HD + h];
    }
#pragma unroll
    for (int e = 0; e < NEXP; ++e) {
#pragma unroll
        for (int s = 32; s > 0; s >>= 1) acc[e] += __shfl_xor(acc[e], s, 64);
    }
    if (lane == 0) {
        int b0 = 0; float l0 = acc[0];
#pragma unroll
        for (int e = 1; e < NEXP; ++e) if (acc[e] > l0) { l0 = acc[e]; b0 = e; }
        int b1 = (b0 == 0) ? 1 : 0; float l1 = acc[b1];
#pragma unroll
        for (int e = 0; e < NEXP; ++e) {
            if (e == b0 || e == b1) continue;
            if (acc[e] > l1) { l1 = acc[e]; b1 = e; }
        }
        // renormalized top-2 softmax weights: w0 = e^l0/(e^l0+e^l1)
        float w0 = 1.f / (1.f + expf(l1 - l0));
        float w1 = 1.f - w0;
        topk_idx[2 * t] = b0; topk_idx[2 * t + 1] = b1;
        topk_w[2 * t] = w0;  topk_w[2 * t + 1] = w1;
        atomicAdd(&counts[b0], 1);
        atomicAdd(&counts[b1], 1);
    }
}

// ---------------- K2: exclusive scan + pad rows ----------------
__global__ void scan_kernel(const int* __restrict__ counts, int* __restrict__ offsets,
                            int* __restrict__ rows) {
    if (threadIdx.x == 0) {
        int off = 0;
#pragma unroll
        for (int e = 0; e < NEXP; ++e) { offsets[e] = off; off += counts[e]; }
    }
    if (threadIdx.x < SLOT_PAD) rows[NSLOT + threadIdx.x] = 0;
}

// ---------------- K3: slot assignment ----------------
__global__ void assign_kernel(const int* __restrict__ topk_idx, const int* __restrict__ offsets,
                              int* __restrict__ counts2, int* __restrict__ rows,
                              int* __restrict__ slot_of) {
    int i = blockIdx.x * 256 + threadIdx.x;   // 0..4095
    int e = topk_idx[i];
    int pos = atomicAdd(&counts2[e], 1);
    int slot = offsets[e] + pos;
    rows[slot] = i >> 1;       // token id
    slot_of[i] = slot;
}

// ---------------- K4: x fp32 -> bf16 ----------------
__global__ void cvt_x_kernel(const float* __restrict__ x, unsigned short* __restrict__ xbf) {
    int i = blockIdx.x * 256 + threadIdx.x;   // each handles 4 floats
    f32x4 v = ((const f32x4*)x)[i];
    s16x4 o;
#pragma unroll
    for (int j = 0; j < 4; ++j) o[j] = (short)f2bf(v[j]);
    ((s16x4*)xbf)[i] = o;
}

// ---------------- K5: fused GEMM1 (g,u) + SwiGLU -> h (bf16) ----------------
__global__ __launch_bounds__(256)
void gemm1_kernel(const unsigned short* __restrict__ xbf, const float* __restrict__ w1,
                  const float* __restrict__ w3, const int* __restrict__ counts,
                  const int* __restrict__ offsets, const int* __restrict__ rows,
                  unsigned short* __restrict__ hbuf) {
    const int NT = ID / BN;       // 28
    const int MT = NTOK / BM;     // 16
    int bid = blockIdx.x;
    int e = bid / (MT * NT);
    int rem = bid - e * (MT * NT);
    int mt = rem / NT;
    int nt = rem - mt * NT;
    int n_e = counts[e];
    int m0 = mt * BM;
    if (m0 >= n_e) return;
    int off = offsets[e];
    int n0 = nt * BN;

    __shared__ unsigned short As[BM][BK];
    __shared__ unsigned short B1s[BN][BK];
    __shared__ unsigned short B3s[BN][BK];

    int tid = threadIdx.x;
    int lane = tid & 63;
    int wid = tid >> 6;
    int wm = (wid >> 1) * 64;
    int wn = (wid & 1) * 64;

    f32x4 accg[4][4] = {};
    f32x4 accu[4][4] = {};

    // A staging: 2 rows/thread, 16B each
    int ar = tid >> 2;
    int ac8 = (tid & 3) * 8;
    int tok0 = rows[off + m0 + ar];         // pad region guarantees in-bounds
    int tok1 = rows[off + m0 + 64 + ar];
    const unsigned short* a0 = xbf + (size_t)tok0 * HD + ac8;
    const unsigned short* a1 = xbf + (size_t)tok1 * HD + ac8;

    // B staging: 4 rows/thread/matrix, fp32->bf16 on the fly
    int br = tid >> 3;
    int bc4 = (tid & 7) * 4;
    size_t wbase = ((size_t)e * ID + n0) * HD + bc4;
    const float* b1p = w1 + wbase + (size_t)br * HD;
    const float* b3p = w3 + wbase + (size_t)br * HD;

    int lr = lane & 15;
    int lk = (lane >> 4) * 8;

    for (int k0 = 0; k0 < HD; k0 += BK) {
        *(i32x4*)&As[ar][ac8]      = *(const i32x4*)(a0 + k0);
        *(i32x4*)&As[64 + ar][ac8] = *(const i32x4*)(a1 + k0);
#pragma unroll
        for (int p = 0; p < 4; ++p) {
            f32x4 v1 = *(const f32x4*)(b1p + (size_t)(32 * p) * HD + k0);
            f32x4 v3 = *(const f32x4*)(b3p + (size_t)(32 * p) * HD + k0);
            s16x4 o1, o3;
#pragma unroll
            for (int j = 0; j < 4; ++j) { o1[j] = (short)f2bf(v1[j]); o3[j] = (short)f2bf(v3[j]); }
            *(s16x4*)&B1s[br + 32 * p][bc4] = o1;
            *(s16x4*)&B3s[br + 32 * p][bc4] = o3;
        }
        __syncthreads();
        s16x8 a[4], b1v[4], b3v[4];
#pragma unroll
        for (int f = 0; f < 4; ++f) {
            a[f]   = *(const s16x8*)&As[wm + f * 16 + lr][lk];
            b1v[f] = *(const s16x8*)&B1s[wn + f * 16 + lr][lk];
            b3v[f] = *(const s16x8*)&B3s[wn + f * 16 + lr][lk];
        }
#pragma unroll
        for (int fm = 0; fm < 4; ++fm)
#pragma unroll
            for (int fn = 0; fn < 4; ++fn) {
                accg[fm][fn] = __builtin_amdgcn_mfma_f32_16x16x32_bf16(a[fm], b1v[fn], accg[fm][fn], 0, 0, 0);
                accu[fm][fn] = __builtin_amdgcn_mfma_f32_16x16x32_bf16(a[fm], b3v[fn], accu[fm][fn], 0, 0, 0);
            }
        __syncthreads();
    }

    int lc = lane & 15;
    int lr4 = (lane >> 4) * 4;
#pragma unroll
    for (int fm = 0; fm < 4; ++fm) {
#pragma unroll
        for (int r = 0; r < 4; ++r) {
            int row = wm + fm * 16 + lr4 + r;
            if (m0 + row < n_e) {
                size_t base = (size_t)(off + m0 + row) * ID + n0 + wn;
#pragma unroll
                for (int fn = 0; fn < 4; ++fn) {
                    float g = accg[fm][fn][r];
                    float u = accu[fm][fn][r];
                    float hv = g * u / (1.f + expf(-g));   // silu(g)*u
                    hbuf[base + fn * 16 + lc] = f2bf(hv);
                }
            }
        }
    }
}

// ---------------- K6: GEMM2 h @ w2^T -> per-slot fp32 ----------------
__global__ __launch_bounds__(256)
void gemm2_kernel(const unsigned short* __restrict__ hbuf, const float* __restrict__ w2,
                  const int* __restrict__ counts, const int* __restrict__ offsets,
                  float* __restrict__ out2) {
    const int NT = HD / BN;       // 8
    const int MT = NTOK / BM;     // 16
    int bid = blockIdx.x;
    int e = bid / (MT * NT);
    int rem = bid - e * (MT * NT);
    int mt = rem / NT;
    int nt = rem - mt * NT;
    int n_e = counts[e];
    int m0 = mt * BM;
    if (m0 >= n_e) return;
    int off = offsets[e];
    int n0 = nt * BN;

    __shared__ unsigned short As[BM][BK];
    __shared__ unsigned short Bs[BN][BK];

    int tid = threadIdx.x;
    int lane = tid & 63;
    int wid = tid >> 6;
    int wm = (wid >> 1) * 64;
    int wn = (wid & 1) * 64;

    f32x4 acc[4][4] = {};

    int ar = tid >> 2;
    int ac8 = (tid & 3) * 8;
    const unsigned short* a0 = hbuf + (size_t)(off + m0 + ar) * ID + ac8;
    const unsigned short* a1 = hbuf + (size_t)(off + m0 + 64 + ar) * ID + ac8;

    int br = tid >> 3;
    int bc4 = (tid & 7) * 4;
    const float* bp = w2 + ((size_t)e * HD + n0 + br) * ID + bc4;

    int lr = lane & 15;
    int lk = (lane >> 4) * 8;

    for (int k0 = 0; k0 < ID; k0 += BK) {
        *(i32x4*)&As[ar][ac8]      = *(const i32x4*)(a0 + k0);
        *(i32x4*)&As[64 + ar][ac8] = *(const i32x4*)(a1 + k0);
#pragma unroll
        for (int p = 0; p < 4; ++p) {
            f32x4 v = *(const f32x4*)(bp + (size_t)(32 * p) * ID + k0);
            s16x4 o;
#pragma unroll
            for (int j = 0; j < 4; ++j) o[j] = (short)f2bf(v[j]);
            *(s16x4*)&Bs[br + 32 * p][bc4] = o;
        }
        __syncthreads();
        s16x8 a[4], b[4];
#pragma unroll
        for (int f = 0; f < 4; ++f) {
            a[f] = *(const s16x8*)&As[wm + f * 16 + lr][lk];
            b[f] = *(const s16x8*)&Bs[wn + f * 16 + lr][lk];
        }
#pragma unroll
        for (int fm = 0; fm < 4; ++fm)
#pragma unroll
            for (int fn = 0; fn < 4; ++fn)
                acc[fm][fn] = __builtin_amdgcn_mfma_f32_16x16x32_bf16(a[fm], b[fn], acc[fm][fn], 0, 0, 0);
        __syncthreads();
    }

    int lc = lane & 15;
    int lr4 = (lane >> 4) * 4;
#pragma unroll
    for (int fm = 0; fm < 4; ++fm) {
#pragma unroll
        for (int r = 0; r < 4; ++r) {
            int row = wm + fm * 16 + lr4 + r;
            if (m0 + row < n_e) {
                float* dst = out2 + (size_t)(off + m0 + row) * HD + n0 + wn;
#pragma unroll
                for (int fn = 0; fn < 4; ++fn)
                    dst[fn * 16 + lc] = acc[fm][fn][r];
            }
        }
    }
}

// ---------------- K7: weighted combine ----------------
__global__ void combine_kernel(const float* __restrict__ out2, const int* __restrict__ slot_of,
                               const float* __restrict__ topk_w, float* __restrict__ y) {
    int i = blockIdx.x * 256 + threadIdx.x;   // over NTOK*HD/4
    int t = i >> 8;           // HD/4 = 256 float4 per token
    int c = i & 255;
    int s0 = slot_of[2 * t], s1 = slot_of[2 * t + 1];
    float w0 = topk_w[2 * t], w1 = topk_w[2 * t + 1];
    f32x4 a = ((const f32x4*)(out2 + (size_t)s0 * HD))[c];
    f32x4 b = ((const f32x4*)(out2 + (size_t)s1 * HD))[c];
    f32x4 o;
#pragma unroll
    for (int j = 0; j < 4; ++j) o[j] = w0 * a[j] + w1 * b[j];
    ((f32x4*)(y + (size_t)t * HD))[c] = o;
}

extern "C" void kernel_launch(void* const* d_in, const int* in_sizes, int n_in,
                              void* d_out, int out_size, void* d_ws, size_t ws_size,
                              hipStream_t stream) {
    (void)in_sizes; (void)n_in; (void)out_size; (void)ws_size;
    const float* x  = (const float*)d_in[0];
    const float* wg = (const float*)d_in[1];
    const float* w1 = (const float*)d_in[2];
    const float* w3 = (const float*)d_in[3];
    const float* w2 = (const float*)d_in[4];
    float* y = (float*)d_out;

    char* ws = (char*)d_ws;
    int*   counts   = (int*)(ws + 0);       // 8 ints
    int*   counts2  = (int*)(ws + 32);      // 8 ints
    int*   offsets  = (int*)(ws + 64);      // 8 ints
    int*   topk_idx = (int*)(ws + 128);                        // 4096 ints
    float* topk_w   = (float*)(ws + 128 + (size_t)NSLOT * 4);  // 4096 floats
    int*   rows     = (int*)(ws + 128 + (size_t)NSLOT * 8);    // 4224 ints
    int*   slot_of  = (int*)(ws + 128 + (size_t)NSLOT * 8 + (size_t)NSLOT_ALLOC * 4);
    size_t off_xbf = 128 + (size_t)NSLOT * 12 + (size_t)NSLOT_ALLOC * 4;
    off_xbf = (off_xbf + 255) & ~(size_t)255;
    unsigned short* xbf = (unsigned short*)(ws + off_xbf);
    size_t off_h = off_xbf + (size_t)NTOK * HD * 2;
    unsigned short* hbuf = (unsigned short*)(ws + off_h);
    size_t off_o2 = off_h + (size_t)NSLOT_ALLOC * ID * 2;
    float* out2 = (float*)(ws + off_o2);

    init_kernel<<<1, 64, 0, stream>>>(counts);
    router_kernel<<<NTOK, 64, 0, stream>>>(x, wg, topk_idx, topk_w, counts);
    scan_kernel<<<1, 128, 0, stream>>>(counts, offsets, rows);
    assign_kernel<<<NSLOT / 256, 256, 0, stream>>>(topk_idx, offsets, counts2, rows, slot_of);
    cvt_x_kernel<<<(NTOK * HD / 4) / 256, 256, 0, stream>>>(x, xbf);
    gemm1_kernel<<<NEXP * (NTOK / BM) * (ID / BN), 256, 0, stream>>>(xbf, w1, w3, counts, offsets, rows, hbuf);
    gemm2_kernel<<<NEXP * (NTOK / BM) * (HD / BN), 256, 0, stream>>>(hbuf, w2, counts, offsets, out2);
    combine_kernel<<<(NTOK * HD / 4) / 256, 256, 0, stream>>>(out2, slot_of, topk_w, y);
}